// Round 1
// baseline (5232.726 us; speedup 1.0000x reference)
//
#include <hip/hip_runtime.h>

// LSTM fused persistent kernel for MI355X.
// 16 groups x 16 CUs; group g owns batches [16g,16g+16); CU within group owns
// 32 hidden units (128 gate-cols). Wh fp16 fragments live in VGPRs for all 512
// steps. h crosses CUs through LLC via agent-scope atomics + flag barrier.

typedef __attribute__((ext_vector_type(8))) _Float16 f16x8;
typedef __attribute__((ext_vector_type(4))) float f32x4;

#define NTHR 256
constexpr int T_LEN = 512, EMB = 1024, HID = 512, NCLS = 10;
constexpr int GSIZE = 16;   // CUs per group
constexpr int NGRP  = 16;   // groups
constexpr int BPG   = 16;   // batches per group
constexpr int UPC   = 32;   // hidden units per CU
constexpr int COLS_PC = 128;
constexpr int NKT = 16;     // K tiles of 32 (HID=512)

__device__ __forceinline__ float sigmf(float x)    { return 1.f / (1.f + __expf(-x)); }
__device__ __forceinline__ float tanhfast(float x) { return 1.f - 2.f / (__expf(2.f * x) + 1.f); }

__global__ __launch_bounds__(NTHR, 2) void lstm_fused(
    const int* __restrict__ xtok, const float* __restrict__ emb,
    const float* __restrict__ Wgx, const float* __restrict__ Wgh, const float* __restrict__ b_g,
    const float* __restrict__ Wix, const float* __restrict__ Wih, const float* __restrict__ b_i,
    const float* __restrict__ Wfx, const float* __restrict__ Wfh, const float* __restrict__ b_f,
    const float* __restrict__ Wox, const float* __restrict__ Woh, const float* __restrict__ b_o,
    const float* __restrict__ Wph, const float* __restrict__ b_p,
    float* __restrict__ out, unsigned* __restrict__ flags, _Float16* __restrict__ hbuf)
{
  const int tid  = threadIdx.x;
  const int wv   = tid >> 6;     // wave 0..3
  const int lane = tid & 63;
  const int q    = lane >> 4;    // lane quarter
  const int c    = lane & 15;
  const int wg   = blockIdx.x;
  const int grp  = wg >> 4;
  const int cu   = wg & 15;

  __shared__ __align__(16) _Float16 h_lds[BPG * HID];   // 16 KB, fragment order
  __shared__ __align__(16) _Float16 hst[64 * 8];        // 1 KB CU h-chunk staging
  __shared__ unsigned char xl[BPG][T_LEN];              // 8 KB packed tokens
  __shared__ float projl[3][COLS_PC];                   // 1.5 KB

  // ---- pack this group's tokens into LDS (u8)
  for (int idx = tid; idx < BPG * T_LEN; idx += NTHR) {
    int bl = idx >> 9, tt = idx & (T_LEN - 1);
    xl[bl][tt] = (unsigned char)xtok[(grp * BPG + bl) * T_LEN + tt];
  }

  // ---- proj[v][cc] = b_gate[j] + emb[v] . Wx[:,gate,j]   (3-row lookup table)
  if (tid < COLS_PC) {
    int cc = tid, w2 = cc >> 5, nt = (cc >> 4) & 1, c2 = cc & 15;
    int gate = nt * 2 + (c2 >> 3);
    int j = cu * UPC + w2 * 8 + (c2 & 7);
    const float* Wx = gate == 0 ? Wgx : gate == 1 ? Wix : gate == 2 ? Wfx : Wox;
    const float* bb = gate == 0 ? b_g : gate == 1 ? b_i : gate == 2 ? b_f : b_o;
    for (int v = 0; v < 3; ++v) {
      float s = bb[j];
      const float* er = emb + v * EMB;
      #pragma unroll 4
      for (int e = 0; e < EMB; ++e) s = fmaf(er[e], Wx[e * HID + j], s);
      projl[v][cc] = s;
    }
  }

  // ---- Wh B-fragments into registers (fp32 -> fp16), kept for all 512 steps.
  // Convention: (lane-quarter q, elem jj) -> k = 8q + jj, applied identically to
  // A and B, so the HW's internal k-permutation cancels.
  f16x8 Bf[2][NKT];
  {
    int g0 = c >> 3;
    int j = cu * UPC + wv * 8 + (c & 7);
    #pragma unroll
    for (int nt = 0; nt < 2; ++nt) {
      int gate = nt * 2 + g0;
      const float* W = gate == 0 ? Wgh : gate == 1 ? Wih : gate == 2 ? Wfh : Woh;
      #pragma unroll
      for (int kt = 0; kt < NKT; ++kt) {
        f16x8 tmp;
        #pragma unroll
        for (int jj = 0; jj < 8; ++jj)
          tmp[jj] = (_Float16)W[(kt * 32 + q * 8 + jj) * HID + j];
        Bf[nt][kt] = tmp;
      }
    }
  }

  float cst[4] = {0.f, 0.f, 0.f, 0.f};     // c-state, rows q*4+r
  _Float16* hb0 = hbuf + grp * 2 * (BPG * HID);
  _Float16* hb1 = hb0 + BPG * HID;
  unsigned* fl = flags + grp * GSIZE;
  __syncthreads();

  for (int t = 0; t < T_LEN; ++t) {
    // ---- stage h_prev (fragment-ordered in global) into LDS; t=0 has h=0
    if (t > 0) {
      const unsigned long long* src =
          (const unsigned long long*)((t & 1) ? hb1 : hb0);
      unsigned long long* dstl = (unsigned long long*)h_lds;
      #pragma unroll
      for (int it = 0; it < 8; ++it) {
        int u = wv * 512 + it * 64 + lane;
        dstl[u] = __hip_atomic_load(src + u, __ATOMIC_RELAXED, __HIP_MEMORY_SCOPE_AGENT);
      }
    }
    __syncthreads();

    // ---- gates tile: 16 batches x 32 cols per wave (2 n-tiles), K=512
    f32x4 acc0 = {0.f, 0.f, 0.f, 0.f}, acc1 = {0.f, 0.f, 0.f, 0.f};
    if (t > 0) {
      #pragma unroll
      for (int kt = 0; kt < NKT; ++kt) {
        f16x8 a = *(const f16x8*)(h_lds + (kt * 64 + lane) * 8);
        acc0 = __builtin_amdgcn_mfma_f32_16x16x32_f16(a, Bf[0][kt], acc0, 0, 0, 0);
        acc1 = __builtin_amdgcn_mfma_f32_16x16x32_f16(a, Bf[1][kt], acc1, 0, 0, 0);
      }
    }

    // ---- nonlinearity + state update. C/D layout: col=lane&15, row=4q+reg.
    // nt0 cols = [g x8 | i x8], nt1 cols = [f x8 | o x8] for this wave's 8 units.
    bool lo = (c < 8);
    #pragma unroll
    for (int r = 0; r < 4; ++r) {
      int bl = q * 4 + r;                     // batch row in tile
      int v = xl[bl][t];
      float p0 = acc0[r] + projl[v][wv * 32 + c];
      float p1 = acc1[r] + projl[v][wv * 32 + 16 + c];
      float p0x = __shfl_xor(p0, 8);
      float p1x = __shfl_xor(p1, 8);
      float gg = lo ? p0  : p0x;
      float ii = lo ? p0x : p0;
      float ff = lo ? p1  : p1x;
      float oo = lo ? p1x : p1;
      gg = tanhfast(gg); ii = sigmf(ii); ff = sigmf(ff); oo = sigmf(oo);
      float cn = fmaf(cst[r], ff, gg * ii);
      cst[r] = cn;
      float hv = tanhfast(cn) * oo;
      // h(bl, j=cu*32+wv*8+(c&7)) -> chunk [kt=cu][lane_a=wv*16+bl][jj=c]
      if (lo) hst[(wv * 16 + bl) * 8 + c] = (_Float16)hv;
    }
    __syncthreads();

    // ---- wave0 publishes this CU's 1KB h-chunk to LLC, then flag barrier
    if (wv == 0) {
      unsigned long long* dst =
          (unsigned long long*)((t & 1) ? hb0 : hb1) + cu * 128;
      const unsigned long long* s2 = (const unsigned long long*)hst;
      __hip_atomic_store(dst + lane,      s2[lane],      __ATOMIC_RELAXED, __HIP_MEMORY_SCOPE_AGENT);
      __hip_atomic_store(dst + 64 + lane, s2[64 + lane], __ATOMIC_RELAXED, __HIP_MEMORY_SCOPE_AGENT);
      if (lane == 0)
        __hip_atomic_store(fl + cu, (unsigned)(t + 1), __ATOMIC_RELEASE, __HIP_MEMORY_SCOPE_AGENT);
      for (;;) {
        unsigned vf = (lane < GSIZE)
            ? __hip_atomic_load(fl + lane, __ATOMIC_RELAXED, __HIP_MEMORY_SCOPE_AGENT)
            : 0xffffffffu;
        if (__all(vf >= (unsigned)(t + 1))) break;
        __builtin_amdgcn_s_sleep(1);
      }
      __threadfence();   // acquire: invalidate stale L1/L2 before next-step reads
    }
    __syncthreads();
  }

  // ---- epilogue: p = h_T @ W_ph + b_p ; log_softmax. WG cu handles batch grp*16+cu.
  // h_T is in hb0 (step 511 wrote buffer 0).
  if (wv == 0) {
    float pc[NCLS];
    #pragma unroll
    for (int k2 = 0; k2 < NCLS; ++k2) pc[k2] = 0.f;
    int kt = lane >> 2, qa = lane & 3;        // each lane: 8 consecutive j
    const unsigned long long* hs =
        (const unsigned long long*)hb0 + (kt * 64 + qa * 16 + cu) * 2;
    unsigned long long d0 = __hip_atomic_load(hs,     __ATOMIC_RELAXED, __HIP_MEMORY_SCOPE_AGENT);
    unsigned long long d1 = __hip_atomic_load(hs + 1, __ATOMIC_RELAXED, __HIP_MEMORY_SCOPE_AGENT);
    _Float16 hh[8];
    __builtin_memcpy(&hh[0], &d0, 8);
    __builtin_memcpy(&hh[4], &d1, 8);
    int jbase = kt * 32 + qa * 8;
    #pragma unroll
    for (int jj = 0; jj < 8; ++jj) {
      float hv = (float)hh[jj];
      const float* wr = Wph + (jbase + jj) * NCLS;
      #pragma unroll
      for (int k2 = 0; k2 < NCLS; ++k2) pc[k2] = fmaf(hv, wr[k2], pc[k2]);
    }
    #pragma unroll
    for (int off = 32; off > 0; off >>= 1) {
      #pragma unroll
      for (int k2 = 0; k2 < NCLS; ++k2) pc[k2] += __shfl_down(pc[k2], off);
    }
    if (lane == 0) {
      float mx = -1e30f;
      #pragma unroll
      for (int k2 = 0; k2 < NCLS; ++k2) { pc[k2] += b_p[k2]; mx = fmaxf(mx, pc[k2]); }
      float se = 0.f;
      #pragma unroll
      for (int k2 = 0; k2 < NCLS; ++k2) se += __expf(pc[k2] - mx);
      float ls = mx + __logf(se);
      int b = grp * BPG + cu;
      #pragma unroll
      for (int k2 = 0; k2 < NCLS; ++k2) out[b * NCLS + k2] = pc[k2] - ls;
    }
  }
}

extern "C" void kernel_launch(void* const* d_in, const int* in_sizes, int n_in,
                              void* d_out, int out_size, void* d_ws, size_t ws_size,
                              hipStream_t stream) {
  (void)in_sizes; (void)n_in; (void)out_size; (void)ws_size;
  const int*   x   = (const int*)d_in[0];
  const float* emb = (const float*)d_in[1];
  const float* Wgx = (const float*)d_in[2];
  const float* Wgh = (const float*)d_in[3];
  const float* bg  = (const float*)d_in[4];
  const float* Wix = (const float*)d_in[5];
  const float* Wih = (const float*)d_in[6];
  const float* bi  = (const float*)d_in[7];
  const float* Wfx = (const float*)d_in[8];
  const float* Wfh = (const float*)d_in[9];
  const float* bfv = (const float*)d_in[10];
  const float* Wox = (const float*)d_in[11];
  const float* Woh = (const float*)d_in[12];
  const float* bo  = (const float*)d_in[13];
  const float* Wph = (const float*)d_in[14];
  const float* bp  = (const float*)d_in[15];
  float* out = (float*)d_out;

  unsigned* flags = (unsigned*)d_ws;                       // 1 KB, zeroed per launch
  _Float16* hbuf  = (_Float16*)((char*)d_ws + 4096);       // 512 KB h double-buffer

  hipMemsetAsync(d_ws, 0, 1024, stream);                   // reset barrier flags
  lstm_fused<<<dim3(NGRP * GSIZE), dim3(NTHR), 0, stream>>>(
      x, emb, Wgx, Wgh, bg, Wix, Wih, bi, Wfx, Wfh, bfv,
      Wox, Woh, bo, Wph, bp, out, flags, hbuf);
}